// Round 2
// baseline (463.620 us; speedup 1.0000x reference)
//
#include <hip/hip_runtime.h>

// VQEmbedding forward (TRAINING=True):
//   z_e_x [32,256,64,64] f32, codebook [512,256] f32, labels [32] i32
//   out = concat(z_q_x, z_q_x_bar), each [32,256,64,64] f32 — both equal
//   codebook[argmin] in the forward pass.
//
// Reference arithmetic emulated bit-exactly (same as prior passing rounds):
//   - dot: ascending-d fp32 FMA chain per (point, code)  (== sgemm)
//   - in_sqr: fp64 ascending-d fma -> fp32
//   - cb_sqr: fp64 -> fp32
//   - dist = fmaf(-2, acc, fl(insq + cbs_k)); strict < ascending k == first-index tie
//
// R5 restructure: R4 (4 waves, 13 codes/wave, 4 pts/lane) had wide loads but
// only 2048 waves -> 18.5% occupancy, latency-bound (VALUBusy 20%, HBM 27%).
// Now: 512-thread blocks (8 waves), 128 points/block, wave w owns 7 codes
// (8*7=56 >= max class 51, kbase wave-uniform -> SGPR operands), lane owns 2
// consecutive points (dwordx2 loads/stores). Grid = 1024 blocks = 4 blocks/CU
// = 32 waves/CU = 100% occupancy. 14 fp32 acc/thread keeps VGPR <= 64
// (required for 8 waves/SIMD; enforced by __launch_bounds__(512, 8)).

#define D       256
#define KCODES  512
#define HW      4096
#define BATCH   32
#define NPTS    (BATCH * HW)   // 131072
#define NWAVES  8
#define WPW     7              // codes per wave (8*7 = 56 >= max class size 51)
#define PTS     128            // points per block (2 per lane)

__constant__ int c_cls_start[11] = {0, 51, 101, 151, 201, 251, 301, 352, 402, 452, 502};

// Prep: cbT[d][k] = cb[k][d]  (per-d class slice contiguous -> scalar loads),
//       cbs[k] = fl32( fp64 sum_d cb[k][d]^2 )
__global__ __launch_bounds__(256) void prep_kernel(const float* __restrict__ cb,
                                                   float* __restrict__ cbT,
                                                   float* __restrict__ cbs) {
    const int k = blockIdx.x;   // 0..511
    const int d = threadIdx.x;  // 0..255
    float v = cb[k * D + d];
    cbT[(size_t)d * KCODES + k] = v;
    __shared__ double red[256];
    red[d] = (double)v * (double)v;
    __syncthreads();
    for (int s = 128; s > 0; s >>= 1) {
        if (d < s) red[d] += red[d + s];
        __syncthreads();
    }
    if (d == 0) cbs[k] = (float)red[0];
}

__global__ __launch_bounds__(512, 8) void vq_kernel(const float* __restrict__ z,
                                                    const int* __restrict__ labels,
                                                    const float* __restrict__ cbT,
                                                    const float* __restrict__ cbs,
                                                    float* __restrict__ out) {
    const int lane = threadIdx.x & 63;
    const int w    = __builtin_amdgcn_readfirstlane(threadIdx.x >> 6);  // wave 0..7
    const int b    = blockIdx.x >> 5;                 // 32 blocks per image
    const int hw0  = (blockIdx.x & 31) << 7;          // 128-point tile base
    const int p2   = hw0 | (lane << 1);               // this lane's 2 points
    const int lab  = __builtin_amdgcn_readfirstlane(labels[b]);
    const int c0   = c_cls_start[lab];
    const int cnt  = c_cls_start[lab + 1] - c0;       // 50 or 51
    const int kbase = c0 + w * WPW;                   // wave-uniform (SGPR)
    const int myn   = min(WPW, cnt - w * WPW);        // 7,...,7,{1|2}

    const float* __restrict__ xp = z + (size_t)b * (D * HW) + p2;  // x2[d] = xp[d*HW..+1]

    float acc[WPW][2];
#pragma unroll
    for (int j = 0; j < WPW; ++j) {
        acc[j][0] = 0.0f;
        acc[j][1] = 0.0f;
    }

    double xsq0 = 0.0, xsq1 = 0.0;  // ||x||^2 in fp64, ascending d

    // x prefetch pipeline, depth 4 (each entry = 2 points at one d)
    float2 xb[4];
#pragma unroll
    for (int i = 0; i < 4; ++i) xb[i] = *(const float2*)(xp + (size_t)i * HW);

    for (int d = 0; d < D; d += 4) {
        float2 xn[4];
#pragma unroll
        for (int i = 0; i < 4; ++i) {
            int dn = (d + 4 + i) & (D - 1);  // wrap on last chunk (harmless reload)
            xn[i] = *(const float2*)(xp + (size_t)dn * HW);
        }
#pragma unroll
        for (int i = 0; i < 4; ++i) {
            // wave-uniform address -> scalar loads, SGPR FMA operand
            const float* __restrict__ wd = cbT + (size_t)(d + i) * KCODES + kbase;
            const float2 x = xb[i];
            xsq0 = fma((double)x.x, (double)x.x, xsq0);
            xsq1 = fma((double)x.y, (double)x.y, xsq1);
#pragma unroll
            for (int j = 0; j < WPW; ++j) {
                const float c = wd[j];
                acc[j][0] = fmaf(x.x, c, acc[j][0]);  // ascending-d fp32 chain
                acc[j][1] = fmaf(x.y, c, acc[j][1]);
            }
        }
#pragma unroll
        for (int i = 0; i < 4; ++i) xb[i] = xn[i];
    }

    // Emulated reference distance; local argmin over this wave's 7 codes
    __shared__ float sd[NWAVES][PTS];
    __shared__ int   si[NWAVES][PTS];
#pragma unroll
    for (int p = 0; p < 2; ++p) {
        const float insq = (float)(p == 0 ? xsq0 : xsq1);
        float best = __builtin_inff();
        int bi = kbase;
#pragma unroll
        for (int j = 0; j < WPW; ++j) {
            if (j < myn) {
                float T    = insq + cbs[kbase + j];      // fp32 add, RNE
                float dist = fmaf(-2.0f, acc[j][p], T);  // == fl(T - 2*acc)
                if (dist < best) { best = dist; bi = kbase + j; }
            }
        }
        sd[w][(lane << 1) + p] = best;
        si[w][(lane << 1) + p] = bi;
    }
    __syncthreads();

    // Cross-wave argmin (ascending w + strict < == lowest-index tie-break)
    __shared__ int fidx[PTS];
    if (threadIdx.x < PTS) {
        const int pi = threadIdx.x;  // one point per thread
        float fb = sd[0][pi];
        int   fi = si[0][pi];
#pragma unroll
        for (int w2 = 1; w2 < NWAVES; ++w2) {
            float dv = sd[w2][pi];
            if (dv < fb) { fb = dv; fi = si[w2][pi]; }
        }
        fidx[pi] = fi;
    }
    __syncthreads();

    // Epilogue: out0 = out1 = codebook[fidx]; wave w writes d in [32w, 32w+32),
    // each lane writes its 2 points as one dwordx2 per output per d.
    const int f0 = fidx[(lane << 1) + 0];
    const int f1 = fidx[(lane << 1) + 1];

    float* __restrict__ o0 = out + (size_t)b * (D * HW) + p2;
    float* __restrict__ o1 = o0 + (size_t)NPTS * D;
    const int d0 = w * 32;
    const float* __restrict__ cbd = cbT + (size_t)d0 * KCODES;
    for (int d = d0; d < d0 + 32; ++d) {
        float2 v;  // gathers land in a ~204 B class window -> L1
        v.x = cbd[f0];
        v.y = cbd[f1];
        *(float2*)(o0 + (size_t)d * HW) = v;
        *(float2*)(o1 + (size_t)d * HW) = v;
        cbd += KCODES;
    }
}

extern "C" void kernel_launch(void* const* d_in, const int* in_sizes, int n_in,
                              void* d_out, int out_size, void* d_ws, size_t ws_size,
                              hipStream_t stream) {
    const float* z      = (const float*)d_in[0];
    const float* cb     = (const float*)d_in[1];
    const int*   labels = (const int*)d_in[2];
    float* out = (float*)d_out;

    float* cbT = (float*)d_ws;              // 256*512 f32 = 512 KB
    float* cbs = cbT + (size_t)D * KCODES;  // 512 f32

    hipLaunchKernelGGL(prep_kernel, dim3(KCODES), dim3(D), 0, stream, cb, cbT, cbs);
    hipLaunchKernelGGL(vq_kernel, dim3(NPTS / PTS), dim3(512), 0, stream,
                       z, labels, cbT, cbs, out);
}